// Round 9
// baseline (113.361 us; speedup 1.0000x reference)
//
#include <hip/hip_runtime.h>

#define N_TOTAL 16384
#define HALF    8192
#define FEAT    128
#define MARGIN  0.3f
#define NBINS   1024   // NUM_IDS=1000 <= 1024

typedef __attribute__((ext_vector_type(8))) short  short8v;   // 8 x bf16 (4 VGPRs)
typedef __attribute__((ext_vector_type(4))) float  float4v;   // 4 x f32 acc

__device__ __forceinline__ unsigned short f32_to_bf16_rne(float f) {
    unsigned u = __float_as_uint(f);
    u += 0x7FFFu + ((u >> 16) & 1u);
    return (unsigned short)(u >> 16);
}

// ---- DPP cross-lane min/max within 16-lane rows (VALU pipe, not DS) ------
template<int CTRL>
__device__ __forceinline__ float dpp_mov_f(float x) {
    return __int_as_float(__builtin_amdgcn_update_dpp(
        0, __float_as_int(x), CTRL, 0xF, 0xF, true));
}
__device__ __forceinline__ float rowmin16(float x) {
    x = fminf(x, dpp_mov_f<0xB1>(x));    // quad_perm xor1
    x = fminf(x, dpp_mov_f<0x4E>(x));    // quad_perm xor2
    x = fminf(x, dpp_mov_f<0x141>(x));   // ROW_HALF_MIRROR
    x = fminf(x, dpp_mov_f<0x140>(x));   // ROW_MIRROR
    return x;
}
__device__ __forceinline__ float rowmax16(float x) {
    x = fmaxf(x, dpp_mov_f<0xB1>(x));
    x = fmaxf(x, dpp_mov_f<0x4E>(x));
    x = fmaxf(x, dpp_mov_f<0x141>(x));
    x = fmaxf(x, dpp_mov_f<0x140>(x));
    return x;
}

// ---------------------------------------------------------------------------
// histscan: 2 blocks x 1024 (one per modality half). LDS histogram + scan ->
// cursor (bucket starts). Block 0 zeroes accF/accI/ticket.
// ---------------------------------------------------------------------------
__global__ __launch_bounds__(1024) void histscan_kernel(
        const int* __restrict__ targets, int* __restrict__ cursor,
        int* __restrict__ accs /* [accF, accI, ticket] */) {
    __shared__ int lhist[NBINS];
    const int h = blockIdx.x;
    const int t = threadIdx.x;
    lhist[t] = 0;
    __syncthreads();
    const int* tg = targets + (h << 13);
    #pragma unroll
    for (int k = 0; k < 8; ++k)
        atomicAdd(&lhist[tg[k * 1024 + t]], 1);
    __syncthreads();
    const int lane = t & 63, wave = t >> 6;
    int x = lhist[t];
    const int orig = x;
    #pragma unroll
    for (int m = 1; m < 64; m <<= 1) {
        int v = __shfl_up(x, m, 64);
        if (lane >= m) x += v;
    }
    __shared__ int wsum[16];
    if (lane == 63) wsum[wave] = x;
    __syncthreads();
    if (t == 0) {
        int s = 0;
        for (int w = 0; w < 16; ++w) { int v = wsum[w]; wsum[w] = s; s += v; }
        if (h == 0) { accs[0] = 0; accs[1] = 0; accs[2] = 0; }
    }
    __syncthreads();
    cursor[(h << 10) + t] = x - orig + wsum[wave];
}

// ---------------------------------------------------------------------------
// prep: one wave per ORIGINAL row. Claims sorted slot, converts fp32->bf16,
// writes Xb in PANEL-MAJOR layout (panel = 16 rows: [chunk][row][16B]).
// ---------------------------------------------------------------------------
__global__ __launch_bounds__(256) void prep_kernel(
        const float* __restrict__ X, const int* __restrict__ targets,
        int* __restrict__ cursor,
        unsigned* __restrict__ Xb, float* __restrict__ sq, int* __restrict__ labs) {
    const int wave = threadIdx.x >> 6, lane = threadIdx.x & 63;
    const int src = blockIdx.x * 4 + wave;          // original row
    const int h   = src >> 13;
    const int lbl = targets[src];
    int dst;
    if (lane == 0)
        dst = (h << 13) + atomicAdd(&cursor[(h << 10) + lbl], 1);
    dst = __shfl(dst, 0, 64);
    const float2 xv = ((const float2*)(X + (size_t)src * FEAT))[lane];
    unsigned short h0 = f32_to_bf16_rne(xv.x);      // k = 2*lane
    unsigned short h1 = f32_to_bf16_rne(xv.y);      // k = 2*lane+1
    Xb[(dst >> 4) * 1024 + (lane >> 2) * 64 + (dst & 15) * 4 + (lane & 3)] =
        (unsigned)h0 | ((unsigned)h1 << 16);
    float x0 = __uint_as_float((unsigned)h0 << 16);
    float x1 = __uint_as_float((unsigned)h1 << 16);
    float p = x0 * x0 + x1 * x1;
    #pragma unroll
    for (int m = 1; m < 64; m <<= 1) p += __shfl_xor(p, m, 64);
    if (lane == 0) {
        sq[dst]   = p;
        labs[dst] = lbl;
    }
}

// ---------------------------------------------------------------------------
// main: 2 symmetric passes, no atomics/LDS. Wave owns 64 rows (A frags
// resident in VGPRs), sweeps 32 subtiles of 32 cols (1024 cols), double-
// buffered loads. The block's 4 waves sweep the SAME col stream; a barrier
// per iteration keeps them in LOCKSTEP so their loads hit the same lines
// (MSHR merge + L1 reuse -> ~4x less L2 traffic; L2-BW is the bottleneck).
// Register-accumulated min/max, DPP reduce, plain stores to partials.
// ---------------------------------------------------------------------------
__global__ __launch_bounds__(256, 2) void cross_kernel(
        const unsigned short* __restrict__ Xb, const float* __restrict__ sq,
        const int* __restrict__ labs,
        float* __restrict__ pmin, float* __restrict__ pmax) {
    const int t = threadIdx.x;
    const int wave = t >> 6, lane = t & 63;
    const int q = lane >> 4, c = lane & 15;
    const int b    = blockIdx.x;            // 0..511
    const int pass = b >> 8;                // 0: rows=half0, 1: rows=half1
    const int bb   = b & 255;
    const int cc   = bb & 7;                // col-chunk (1024 cols)
    const int rt   = (bb >> 3) * 4 + wave;  // row-tile 0..127
    const int own  = pass ? HALF : 0;
    const int oth  = pass ? 0 : HALF;
    const int ownbase = own + rt * 64;
    const int chunk0  = oth + cc * 1024;    // first col of this wave's sweep

    const uint4* XbV = (const uint4*)Xb;    // panel p = 256 uint4 at p*256

    const float NEG_INF = __int_as_float((int)0xFF800000u);
    const float POS_INF = __int_as_float(0x7F800000);

    // ---- resident A: 64 own rows (4 panels), 64 VGPRs
    short8v af[4][4];                       // [ti][kk]
    const int pA0 = ownbase >> 4;
    #pragma unroll
    for (int ti = 0; ti < 4; ++ti)
        #pragma unroll
        for (int kk = 0; kk < 4; ++kk)
            af[ti][kk] = *(const short8v*)&XbV[(pA0 + ti) * 256 + kk * 64 + lane];

    const int aMin = labs[ownbase], aMax = labs[ownbase + 63];

    float rmin[16], rmax[16];               // per own row (excl. sA term)
    #pragma unroll
    for (int i = 0; i < 16; ++i) { rmin[i] = POS_INF; rmax[i] = NEG_INF; }

    // ---- pipelined B sweep: 32 subtiles of 32 cols
    auto loadsub = [&](int s, short8v (&bfr)[2][4], float (&sB)[2]) {
        const int sub = chunk0 + s * 32;
        const int pB0 = sub >> 4;
        #pragma unroll
        for (int tj = 0; tj < 2; ++tj) {
            #pragma unroll
            for (int kk = 0; kk < 4; ++kk)
                bfr[tj][kk] = *(const short8v*)&XbV[(pB0 + tj) * 256 + kk * 64 + lane];
            sB[tj] = sq[sub + tj * 16 + c];
        }
    };
    auto computesub = [&](int s, short8v (&bfr)[2][4], float (&sB)[2]) {
        const int sub = chunk0 + s * 32;
        const bool overlap = (aMax >= labs[sub]) && (labs[sub + 31] >= aMin);

        float4v acc[4][2] = {};
        #pragma unroll
        for (int kk = 0; kk < 4; ++kk)
            #pragma unroll
            for (int ti = 0; ti < 4; ++ti)
                #pragma unroll
                for (int tj = 0; tj < 2; ++tj)
                    acc[ti][tj] = __builtin_amdgcn_mfma_f32_16x16x32_bf16(
                        af[ti][kk], bfr[tj][kk], acc[ti][tj], 0, 0, 0);

        if (!overlap) {                     // fast path: all pairs negative
            #pragma unroll
            for (int ti = 0; ti < 4; ++ti)
                #pragma unroll
                for (int tj = 0; tj < 2; ++tj)
                    #pragma unroll
                    for (int reg = 0; reg < 4; ++reg) {
                        float v = fmaf(acc[ti][tj][reg], -2.0f, sB[tj]);
                        rmin[ti * 4 + reg] = fminf(rmin[ti * 4 + reg], v);
                    }
        } else {                            // slow path: labels may match
            int tB[2];
            #pragma unroll
            for (int tj = 0; tj < 2; ++tj)
                tB[tj] = labs[sub + tj * 16 + c];
            int tA[16];
            #pragma unroll
            for (int ti = 0; ti < 4; ++ti)
                #pragma unroll
                for (int reg = 0; reg < 4; ++reg)
                    tA[ti * 4 + reg] = labs[ownbase + ti * 16 + q * 4 + reg];
            #pragma unroll
            for (int ti = 0; ti < 4; ++ti)
                #pragma unroll
                for (int tj = 0; tj < 2; ++tj)
                    #pragma unroll
                    for (int reg = 0; reg < 4; ++reg) {
                        int ri = ti * 4 + reg;
                        float v = fmaf(acc[ti][tj][reg], -2.0f, sB[tj]);
                        bool same = (tA[ri] == tB[tj]);
                        rmin[ri] = fminf(rmin[ri], same ? POS_INF : v);
                        rmax[ri] = fmaxf(rmax[ri], same ? v : NEG_INF);
                    }
        }
    };

    short8v bA[2][4], bB[2][4];
    float   sA2[2],   sB2[2];
    loadsub(0, bA, sA2);
    for (int s = 0; s < 32; s += 2) {
        loadsub(s + 1, bB, sB2);            // in flight during compute(bA)
        computesub(s, bA, sA2);
        if (s + 2 < 32) loadsub(s + 2, bA, sA2);  // in flight during compute(bB)
        computesub(s + 1, bB, sB2);
        __syncthreads();                    // lockstep: 4 waves share B lines in L1
    }

    // ---- finalize: reduce across the 16 c-lanes, add ||own row||^2, store
    #pragma unroll
    for (int i = 0; i < 16; ++i) {
        rmin[i] = rowmin16(rmin[i]);
        rmax[i] = rowmax16(rmax[i]);
    }
    if (c == 0) {
        #pragma unroll
        for (int ti = 0; ti < 4; ++ti)
            #pragma unroll
            for (int reg = 0; reg < 4; ++reg) {
                int gi = ownbase + ti * 16 + q * 4 + reg;
                float sA = sq[gi];
                pmin[cc * N_TOTAL + gi] = sA + rmin[ti * 4 + reg]; // +inf stays +inf
                pmax[cc * N_TOTAL + gi] = sA + rmax[ti * 4 + reg]; // -inf stays -inf
            }
    }
}

// ---------------------------------------------------------------------------
// final: reduce the 8 partials per row, loss terms -> global accumulators;
// LAST block (ticket) writes d_out.
// ---------------------------------------------------------------------------
__global__ __launch_bounds__(256) void final_kernel(
        const float* __restrict__ pmin, const float* __restrict__ pmax,
        int* __restrict__ accs /* [accF, accI, ticket] */,
        float* __restrict__ out) {
    const int i = blockIdx.x * 256 + threadIdx.x;
    const int t = threadIdx.x;
    float* accF = (float*)&accs[0];
    int*   accI = &accs[1];
    int*   tick = &accs[2];
    float an2 = pmin[i], ap2 = pmax[i];
    #pragma unroll
    for (int ccp = 1; ccp < 8; ++ccp) {
        an2 = fminf(an2, pmin[ccp * N_TOTAL + i]);
        ap2 = fmaxf(ap2, pmax[ccp * N_TOTAL + i]);
    }
    float ap = sqrtf(fmaxf(ap2, 1e-12f));
    float an = sqrtf(fmaxf(an2, 1e-12f));
    float term = fmaxf(ap - an + MARGIN, 0.0f);
    int cnt = (an >= ap) ? 1 : 0;
    #pragma unroll
    for (int m = 1; m < 64; m <<= 1) {
        term += __shfl_xor(term, m, 64);
        cnt  += __shfl_xor(cnt, m, 64);
    }
    __shared__ float sf[4];
    __shared__ int   si[4];
    if ((t & 63) == 0) { sf[t >> 6] = term; si[t >> 6] = cnt; }
    __syncthreads();
    if (t == 0) {
        atomicAdd(accF, sf[0] + sf[1] + sf[2] + sf[3]);
        atomicAdd(accI, si[0] + si[1] + si[2] + si[3]);
        __threadfence();
        int old = atomicAdd(tick, 1);
        if (old == gridDim.x - 1) {
            __threadfence();
            float S = atomicAdd(accF, 0.0f);
            int   C = atomicAdd(accI, 0);
            out[0] = S / (float)N_TOTAL;
            out[1] = (float)C;
        }
    }
}

extern "C" void kernel_launch(void* const* d_in, const int* in_sizes, int n_in,
                              void* d_out, int out_size, void* d_ws, size_t ws_size,
                              hipStream_t stream) {
    const float* X       = (const float*)d_in[0];   // [16384,128] fp32
    const int*   targets = (const int*)d_in[1];     // [16384] int32
    float* out = (float*)d_out;                     // [2]: loss, correct

    char* ws = (char*)d_ws;
    const size_t XB_BYTES = (size_t)N_TOTAL * FEAT * 2;              // 4 MB
    unsigned* Xb  = (unsigned*)ws;
    float* sq     = (float*)(ws + XB_BYTES);                         // 64 KB
    int* labs     = (int*)(ws + XB_BYTES + 1 * 65536);               // 64 KB
    float* pmin   = (float*)(ws + XB_BYTES + 2 * 65536);             // 512 KB
    float* pmax   = (float*)(ws + XB_BYTES + 2 * 65536 + 8 * N_TOTAL * 4); // 512 KB
    int* cursor   = (int*)(ws + XB_BYTES + 2 * 65536 + 16 * N_TOTAL * 4);  // 8 KB
    int* accs     = cursor + 2 * NBINS;                              // 12 B

    histscan_kernel<<<2, 1024, 0, stream>>>(targets, cursor, accs);
    prep_kernel    <<<4096, 256, 0, stream>>>(X, targets, cursor, Xb, sq, labs);
    cross_kernel   <<<512, 256, 0, stream>>>(
        (const unsigned short*)Xb, sq, labs, pmin, pmax);
    final_kernel   <<<64, 256, 0, stream>>>(pmin, pmax, accs, out);
}